// Round 1
// 1020.275 us; speedup vs baseline: 1.0185x; 1.0185x over previous
//
#include <hip/hip_runtime.h>

#define N_NODES 500000
#define N_EDGES 8000000
#define IN_DIM 128
#define H1 32
#define H2 16
#define NFINE 1954           // fine buckets of 256 nodes (1954*256 = 500224)
#define NCOARSE 62           // node>>13 -> 0..61
#define CAPA 200             // stage capacity, coarse multisplit
#define CAPB 340             // stage capacity, fine multisplit

static __device__ __forceinline__ float bf2f(unsigned short u) {
    return __uint_as_float(((unsigned int)u) << 16);
}
static __device__ __forceinline__ unsigned short f2bf(float f) {
    unsigned int u = __float_as_uint(f);
    unsigned int r = (u + 0x7fffu + ((u >> 16) & 1u)) >> 16;
    return (unsigned short)r;
}
static __device__ __forceinline__ unsigned pack2bf(float a, float b) {
    return (unsigned)f2bf(a) | ((unsigned)f2bf(b) << 16);
}
static __device__ __forceinline__ float ldf(const void* p, int i, bool isf32) {
    return isf32 ? ((const float*)p)[i] : bf2f(((const unsigned short*)p)[i]);
}
// zero a gathered row-quarter when the edge slot is past the end (masked ILP)
static __device__ __forceinline__ uint4 zsel(uint4 u, int v) {
    return v ? u : make_uint4(0u, 0u, 0u, 0u);
}
// unpack 8 bf16 (4 dwords) and accumulate into 8 floats
static __device__ __forceinline__ void acc8(float a[8], uint4 u) {
    unsigned w[4] = {u.x, u.y, u.z, u.w};
#pragma unroll
    for (int p = 0; p < 4; ++p) {
        a[2 * p]     += __uint_as_float(w[p] << 16);
        a[2 * p + 1] += __uint_as_float(w[p] & 0xffff0000u);
    }
}

// ---- dtype sniffer ----
__global__ __launch_bounds__(64) void k_sniff(const unsigned int* __restrict__ x,
                                              int* __restrict__ flag) {
    int bad = 0;
    for (int i = threadIdx.x; i < 1024; i += 64) {
        float v = __uint_as_float((x[i] & 0xffffu) << 16);
        if (!(fabsf(v) < 1e6f)) bad = 1;
    }
    unsigned long long m = __ballot(bad);
    if (threadIdx.x == 0) *flag = (m != 0ull) ? 1 : 0;
}

// ---- fine-bucket histogram via LDS ----
__global__ __launch_bounds__(256) void k_bhist(const int* __restrict__ dst,
                                               int* __restrict__ fhist) {
    __shared__ int h[2048];
    int tid = threadIdx.x;
    for (int i = tid; i < 2048; i += 256) h[i] = 0;
    __syncthreads();
    int i = blockIdx.x * 256 + tid;
    int stride = gridDim.x * 256;
    for (int e = i; e < N_EDGES; e += stride) {
        unsigned d = (unsigned)dst[e];
        if (d < N_NODES) atomicAdd(&h[d >> 8], 1);
    }
    __syncthreads();
    for (int i2 = tid; i2 < 2048; i2 += 256)
        if (h[i2]) atomicAdd(&fhist[i2], h[i2]);
}

// ---- single-block exclusive scan over fine buckets; emits cursors ----
__global__ __launch_bounds__(256) void k_scanf(const int* __restrict__ fhist,
                                               int* __restrict__ fbase,
                                               int* __restrict__ bcur,
                                               int* __restrict__ acur) {
    __shared__ int tmp[256];
    __shared__ int s_run;
    int tid = threadIdx.x;
    if (tid == 0) s_run = 0;
    __syncthreads();
    for (int base = 0; base < 2048; base += 256) {
        int i = base + tid;
        int v = (i < NFINE) ? fhist[i] : 0;
        int val = v;
        tmp[tid] = val;
        __syncthreads();
        for (int o = 1; o < 256; o <<= 1) {
            int t = (tid >= o) ? tmp[tid - o] : 0;
            __syncthreads();
            val += t;
            tmp[tid] = val;
            __syncthreads();
        }
        int run = s_run;
        if (i < NFINE) {
            int ex = run + val - v;
            fbase[i] = ex;
            bcur[i] = ex;
            if ((i & 31) == 0) acur[i >> 5] = ex;
        }
        __syncthreads();
        if (tid == 255) s_run = run + val;
        __syncthreads();
    }
    if (tid == 0) fbase[NFINE] = s_run;
}

// ---- multisplit level A: raw edges -> 62 coarse buckets ----
__global__ __launch_bounds__(256) void k_scatA(const int* __restrict__ src,
                                               const int* __restrict__ dst,
                                               int* __restrict__ acur,
                                               unsigned* __restrict__ ebufA) {
    __shared__ unsigned stage[NCOARSE * CAPA];
    __shared__ int lcnt[NCOARSE], nn[NCOARSE], soff[NCOARSE], sbase[NCOARSE];
    __shared__ int stot;
    int tid = threadIdx.x;
    int cb = blockIdx.x * 8192;
    if (tid < NCOARSE) lcnt[tid] = 0;
    __syncthreads();
    for (int i = 0; i < 32; ++i) {
        int e = cb + (i << 8) + tid;
        if (e < N_EDGES) {
            unsigned d = (unsigned)dst[e], s = (unsigned)src[e];
            if (d < N_NODES) {
                unsigned b = d >> 13;
                unsigned p = ((d & 8191u) << 19) | s;
                int pos = atomicAdd(&lcnt[b], 1);
                if (pos < CAPA) stage[b * CAPA + pos] = p;
                else { int slot = atomicAdd(&acur[b], 1); ebufA[slot] = p; }
            }
        }
    }
    __syncthreads();
    if (tid < NCOARSE) nn[tid] = min(lcnt[tid], CAPA);
    __syncthreads();
    if (tid == 0) {
        int r = 0;
        for (int b = 0; b < NCOARSE; ++b) { soff[b] = r; r += nn[b]; }
        stot = r;
    }
    __syncthreads();
    if (tid < NCOARSE && nn[tid] > 0) sbase[tid] = atomicAdd(&acur[tid], nn[tid]);
    __syncthreads();
    for (int i = tid; i < stot; i += 256) {
        int lo = 0, hi = NCOARSE - 1;
        while (lo < hi) { int mid = (lo + hi + 1) >> 1; if (soff[mid] <= i) lo = mid; else hi = mid - 1; }
        int r = i - soff[lo];
        ebufA[sbase[lo] + r] = stage[lo * CAPA + r];
    }
}

// ---- multisplit level B: coarse -> 32 fine buckets ----
__global__ __launch_bounds__(256) void k_scatB(const unsigned* __restrict__ ebufA,
                                               const int* __restrict__ fbase,
                                               int* __restrict__ bcur,
                                               unsigned* __restrict__ ebufB) {
    __shared__ unsigned stage[32 * CAPB];
    __shared__ int lcnt[32], nn[32], soff[32], sbase[32];
    __shared__ int stot;
    int tid = threadIdx.x;
    int a = blockIdx.x >> 3, sub = blockIdx.x & 7;
    int f0 = a * 32;
    int lb = min(32, NFINE - f0);
    int abase = fbase[f0];
    int aend = fbase[min(f0 + 32, NFINE)];
    for (int cb = abase + sub * 8192; cb < aend; cb += 8 * 8192) {
        if (tid < 32) lcnt[tid] = 0;
        __syncthreads();
        for (int i = 0; i < 32; ++i) {
            int e = cb + (i << 8) + tid;
            if (e < aend) {
                unsigned p = ebufA[e];
                unsigned dl13 = p >> 19;
                unsigned s = p & 0x7FFFFu;
                unsigned j = dl13 >> 8;
                unsigned q = ((dl13 & 255u) << 19) | s;
                int pos = atomicAdd(&lcnt[j], 1);
                if (pos < CAPB) stage[j * CAPB + pos] = q;
                else { int slot = atomicAdd(&bcur[f0 + j], 1); ebufB[slot] = q; }
            }
        }
        __syncthreads();
        if (tid < 32) nn[tid] = (tid < lb) ? min(lcnt[tid], CAPB) : 0;
        __syncthreads();
        if (tid == 0) {
            int r = 0;
            for (int b = 0; b < 32; ++b) { soff[b] = r; r += nn[b]; }
            stot = r;
        }
        __syncthreads();
        if (tid < 32 && nn[tid] > 0) sbase[tid] = atomicAdd(&bcur[f0 + tid], nn[tid]);
        __syncthreads();
        for (int i = tid; i < stot; i += 256) {
            int lo = 0, hi = 31;
            while (lo < hi) { int mid = (lo + hi + 1) >> 1; if (soff[mid] <= i) lo = mid; else hi = mid - 1; }
            int r = i - soff[lo];
            ebufB[sbase[lo] + r] = stage[lo * CAPB + r];
        }
        __syncthreads();
    }
}

// ---- CSR build per fine bucket ----
__global__ __launch_bounds__(256) void k_csr(const unsigned* __restrict__ ebufB,
                                             const int* __restrict__ fbase,
                                             int* __restrict__ csr,
                                             int* __restrict__ off,
                                             float* __restrict__ dinv) {
    __shared__ int cnt[256], ctmp[256], ccur[256];
    int tid = threadIdx.x;
    int b = blockIdx.x;
    int base = fbase[b];
    int n = fbase[b + 1] - base;
    cnt[tid] = 0;
    __syncthreads();
    for (int i = tid; i < n; i += 256) {
        unsigned dl = ebufB[base + i] >> 19;
        atomicAdd(&cnt[dl], 1);
    }
    __syncthreads();
    int v = cnt[tid];
    int val = v;
    ctmp[tid] = val;
    __syncthreads();
    for (int o = 1; o < 256; o <<= 1) {
        int t = (tid >= o) ? ctmp[tid - o] : 0;
        __syncthreads();
        val += t;
        ctmp[tid] = val;
        __syncthreads();
    }
    int excl = val - v;
    off[b * 256 + tid] = base + excl;
    ccur[tid] = excl;
    dinv[b * 256 + tid] = rsqrtf((float)v + 1.0f);
    __syncthreads();
    for (int i = tid; i < n; i += 256) {
        unsigned p = ebufB[base + i];
        unsigned dl = p >> 19;
        int slot = atomicAdd(&ccur[dl], 1);
        csr[base + slot] = (int)(p & 0x7FFFFu);
    }
}

// ---- y1 = (x @ W1) * dinv  -> bf16 rows (32 x bf16 = 64B) ----
__global__ __launch_bounds__(256) void k_gemm1(const void* __restrict__ x,
                                               const void* __restrict__ w1,
                                               const float* __restrict__ dinv,
                                               unsigned* __restrict__ y1b,
                                               const int* __restrict__ flag) {
    __shared__ float wlds[IN_DIM * H1];
    const bool isf32 = (*flag != 0);
    for (int i = threadIdx.x; i < IN_DIM * H1; i += 256) wlds[i] = ldf(w1, i, isf32);
    __syncthreads();
    int node = blockIdx.x * 256 + threadIdx.x;
    if (node >= N_NODES) return;
    float acc[H1];
#pragma unroll
    for (int j = 0; j < H1; ++j) acc[j] = 0.f;
    if (isf32) {
        const float4* xr = reinterpret_cast<const float4*>((const float*)x + (size_t)node * IN_DIM);
#pragma unroll
        for (int kk = 0; kk < IN_DIM / 4; ++kk) {
            float4 v = xr[kk];
            float xe[4] = {v.x, v.y, v.z, v.w};
#pragma unroll
            for (int p = 0; p < 4; ++p) {
                const float* wr = &wlds[(kk * 4 + p) * H1];
#pragma unroll
                for (int j = 0; j < H1; ++j) acc[j] += xe[p] * wr[j];
            }
        }
    } else {
        const uint4* xr = reinterpret_cast<const uint4*>((const unsigned short*)x + (size_t)node * IN_DIM);
#pragma unroll
        for (int kk = 0; kk < IN_DIM / 8; ++kk) {
            uint4 xv = xr[kk];
            unsigned uu[4] = {xv.x, xv.y, xv.z, xv.w};
#pragma unroll
            for (int p = 0; p < 4; ++p) {
                float xlo = __uint_as_float(uu[p] << 16);
                float xhi = __uint_as_float(uu[p] & 0xffff0000u);
                const float* w0 = &wlds[(kk * 8 + p * 2) * H1];
                const float* w1r = w0 + H1;
#pragma unroll
                for (int j = 0; j < H1; ++j) acc[j] += xlo * w0[j];
#pragma unroll
                for (int j = 0; j < H1; ++j) acc[j] += xhi * w1r[j];
            }
        }
    }
    float s = dinv[node];
    unsigned o[16];
#pragma unroll
    for (int q = 0; q < 16; ++q) o[q] = pack2bf(acc[2*q] * s, acc[2*q+1] * s);
    uint4* op = reinterpret_cast<uint4*>(y1b + (size_t)node * 16);
#pragma unroll
    for (int r = 0; r < 4; ++r) op[r] = make_uint4(o[4*r], o[4*r+1], o[4*r+2], o[4*r+3]);
}

// ---- pull layer 1: 4 lanes/node, uint4 (16B) row-quarter gathers.
//      One gather inst = 16 full 64B lines/wave (4x line-MLP vs 16-lane/dword
//      layout). Masked ILP-4 (clamped idx + cndmask-zero) keeps the load batch
//      full on the remainder. Fused relu + GEMM2 via padded LDS h-buffer. ----
__global__ __launch_bounds__(256) void k_pull1(const int* __restrict__ off,
                                               const int* __restrict__ csr,
                                               const unsigned* __restrict__ y1b,
                                               const float* __restrict__ dinv,
                                               const void* __restrict__ b1,
                                               const void* __restrict__ w2,
                                               unsigned* __restrict__ y2b,
                                               const int* __restrict__ flag) {
    __shared__ float w2l[H1 * H2];
    __shared__ float b1l[H1];
    __shared__ float hbuf[64 * 33];      // stride 33: conflict-free at 16 grp/wave
    const bool isf32 = (*flag != 0);
    int tid = threadIdx.x;
    for (int i = tid; i < H1 * H2; i += 256) w2l[i] = ldf(w2, i, isf32);
    if (tid < H1) b1l[tid] = ldf(b1, tid, isf32);
    __syncthreads();

    const int r = tid & 3;               // lane within node: dims [8r, 8r+8)
    const int g = tid >> 2;              // node slot in block (0..63)
    const int node = blockIdx.x * 64 + g;
    if (node >= N_NODES) return;

    float a[8];
#pragma unroll
    for (int p = 0; p < 8; ++p) a[p] = 0.f;

    const int beg = off[node], end = off[node + 1];
    const unsigned* yb = y1b + 4 * r;
    for (int j = beg; j < end; j += 4) {
        const int e1 = end - 1;
        int i1 = min(j + 1, e1), i2 = min(j + 2, e1), i3 = min(j + 3, e1);
        int s0 = csr[j], s1 = csr[i1], s2 = csr[i2], s3 = csr[i3];
        uint4 u0 = *reinterpret_cast<const uint4*>(yb + (size_t)s0 * 16);
        uint4 u1 = *reinterpret_cast<const uint4*>(yb + (size_t)s1 * 16);
        uint4 u2 = *reinterpret_cast<const uint4*>(yb + (size_t)s2 * 16);
        uint4 u3 = *reinterpret_cast<const uint4*>(yb + (size_t)s3 * 16);
        u1 = zsel(u1, j + 1 < end);
        u2 = zsel(u2, j + 2 < end);
        u3 = zsel(u3, j + 3 < end);
        acc8(a, u0); acc8(a, u1); acc8(a, u2); acc8(a, u3);
    }
    // self term (pre-scaled by dinv in gemm1)
    uint4 su = *reinterpret_cast<const uint4*>(yb + (size_t)node * 16);
    acc8(a, su);

    const float sc = dinv[node];
    float* hb = &hbuf[g * 33];
#pragma unroll
    for (int p = 0; p < 8; ++p) {
        float h = sc * a[p] + b1l[8 * r + p];
        hb[8 * r + p] = h > 0.f ? h : 0.f;   // same-wave readers only
    }
    float z[4];
#pragma unroll
    for (int c = 0; c < 4; ++c) z[c] = 0.f;
#pragma unroll
    for (int k = 0; k < H1; ++k) {
        float hv = hb[k];
#pragma unroll
        for (int c = 0; c < 4; ++c) z[c] += hv * w2l[k * H2 + 4 * r + c];
    }
    uint2 o;
    o.x = pack2bf(sc * z[0], sc * z[1]);
    o.y = pack2bf(sc * z[2], sc * z[3]);
    *reinterpret_cast<uint2*>(y2b + (size_t)node * 8 + 2 * r) = o;
}

// ---- pull layer 2: 2 lanes/node, uint4 (16B) half-row gathers (32 nodes/wave),
//      masked ILP-4, fused relu + FC + log_softmax ----
__global__ __launch_bounds__(256) void k_pull2(const int* __restrict__ off,
                                               const int* __restrict__ csr,
                                               const unsigned* __restrict__ y2b,
                                               const float* __restrict__ dinv,
                                               const void* __restrict__ b2,
                                               const void* __restrict__ wfc,
                                               const void* __restrict__ bfc,
                                               void* __restrict__ out,
                                               const int* __restrict__ flag) {
    __shared__ float wl[H2 * 2];
    __shared__ float b2l[H2];
    __shared__ float bfl[2];
    const bool isf32 = (*flag != 0);
    int tid = threadIdx.x;
    if (tid < H2 * 2) wl[tid] = ldf(wfc, tid, isf32);
    if (tid < H2) b2l[tid] = ldf(b2, tid, isf32);
    if (tid < 2) bfl[tid] = ldf(bfc, tid, isf32);
    __syncthreads();

    const int r = tid & 1;               // lane within node: dims [8r, 8r+8)
    const int node = blockIdx.x * 128 + (tid >> 1);
    if (node >= N_NODES) return;

    float a[8];
#pragma unroll
    for (int p = 0; p < 8; ++p) a[p] = 0.f;

    const int beg = off[node], end = off[node + 1];
    const unsigned* yb = y2b + 4 * r;
    for (int j = beg; j < end; j += 4) {
        const int e1 = end - 1;
        int i1 = min(j + 1, e1), i2 = min(j + 2, e1), i3 = min(j + 3, e1);
        int s0 = csr[j], s1 = csr[i1], s2 = csr[i2], s3 = csr[i3];
        uint4 u0 = *reinterpret_cast<const uint4*>(yb + (size_t)s0 * 8);
        uint4 u1 = *reinterpret_cast<const uint4*>(yb + (size_t)s1 * 8);
        uint4 u2 = *reinterpret_cast<const uint4*>(yb + (size_t)s2 * 8);
        uint4 u3 = *reinterpret_cast<const uint4*>(yb + (size_t)s3 * 8);
        u1 = zsel(u1, j + 1 < end);
        u2 = zsel(u2, j + 2 < end);
        u3 = zsel(u3, j + 3 < end);
        acc8(a, u0); acc8(a, u1); acc8(a, u2); acc8(a, u3);
    }
    // self term (pre-scaled)
    uint4 su = *reinterpret_cast<const uint4*>(yb + (size_t)node * 8);
    acc8(a, su);

    const float sc = dinv[node];
    float l0 = 0.f, l1 = 0.f;
#pragma unroll
    for (int p = 0; p < 8; ++p) {
        float h = sc * a[p] + b2l[8 * r + p];
        h = h > 0.f ? h : 0.f;
        l0 += h * wl[(8 * r + p) * 2];
        l1 += h * wl[(8 * r + p) * 2 + 1];
    }
    l0 += __shfl_xor(l0, 1, 64);         // combine lane pair (same node)
    l1 += __shfl_xor(l1, 1, 64);
    if (r == 0) {
        l0 += bfl[0];
        l1 += bfl[1];
        float mx = fmaxf(l0, l1);
        float lse = mx + logf(__expf(l0 - mx) + __expf(l1 - mx));
        if (isf32) {
            reinterpret_cast<float2*>(out)[node] = make_float2(l0 - lse, l1 - lse);
        } else {
            reinterpret_cast<unsigned*>(out)[node] =
                (unsigned)f2bf(l0 - lse) | ((unsigned)f2bf(l1 - lse) << 16);
        }
    }
}

extern "C" void kernel_launch(void* const* d_in, const int* in_sizes, int n_in,
                              void* d_out, int out_size, void* d_ws, size_t ws_size,
                              hipStream_t stream) {
    const void* x   = d_in[0];
    const int*  ei  = (const int*)d_in[1];
    const void* w1  = d_in[2];
    const void* b1  = d_in[3];
    const void* w2  = d_in[4];
    const void* b2  = d_in[5];
    const void* wfc = d_in[6];
    const void* bfc = d_in[7];
    const int* src = ei;
    const int* dst = ei + N_EDGES;

    // workspace (4B units), ~116 MB. csr overlays ebufA (dead after k_scatB).
    float*    ws    = (float*)d_ws;
    int*      flag  = (int*)ws;
    float*    dinv  = ws + 64;
    int*      fhist = (int*)(ws + 500288);
    int*      fbase = (int*)(ws + 502336);
    int*      acur  = (int*)(ws + 504384);
    int*      bcur  = (int*)(ws + 504448);
    int*      off   = (int*)(ws + 506496);
    unsigned* ebufA = (unsigned*)(ws + 1006784);
    int*      csr   = (int*)(ws + 1006784);     // reuses ebufA
    unsigned* ebufB = (unsigned*)(ws + 9006784);
    unsigned* y1b   = (unsigned*)(ws + 17006784);
    unsigned* y2b   = (unsigned*)(ws + 25010368);

    k_sniff<<<1, 64, 0, stream>>>((const unsigned int*)x, flag);
    hipMemsetAsync(fhist, 0, 2048 * sizeof(int), stream);
    k_bhist<<<256, 256, 0, stream>>>(dst, fhist);
    k_scanf<<<1, 256, 0, stream>>>(fhist, fbase, bcur, acur);
    k_scatA<<<977, 256, 0, stream>>>(src, dst, acur, ebufA);
    k_scatB<<<NCOARSE * 8, 256, 0, stream>>>(ebufA, fbase, bcur, ebufB);
    k_csr<<<NFINE, 256, 0, stream>>>(ebufB, fbase, csr, off, dinv);
    k_gemm1<<<NFINE, 256, 0, stream>>>(x, w1, dinv, y1b, flag);
    k_pull1<<<(N_NODES + 63) / 64, 256, 0, stream>>>(off, csr, y1b, dinv, b1, w2, y2b, flag);
    k_pull2<<<(N_NODES + 127) / 128, 256, 0, stream>>>(off, csr, y2b, dinv, b2, wfc, bfc, d_out, flag);
}

// Round 2
// 1017.863 us; speedup vs baseline: 1.0209x; 1.0024x over previous
//
#include <hip/hip_runtime.h>

#define N_NODES 500000
#define N_EDGES 8000000
#define IN_DIM 128
#define H1 32
#define H2 16
#define NFINE 1954           // fine buckets of 256 nodes (1954*256 = 500224)
#define NCOARSE 62           // node>>13 -> 0..61
#define CAPA 200             // stage capacity, coarse multisplit
#define CAPB 340             // stage capacity, fine multisplit

static __device__ __forceinline__ float bf2f(unsigned short u) {
    return __uint_as_float(((unsigned int)u) << 16);
}
static __device__ __forceinline__ unsigned short f2bf(float f) {
    unsigned int u = __float_as_uint(f);
    unsigned int r = (u + 0x7fffu + ((u >> 16) & 1u)) >> 16;
    return (unsigned short)r;
}
static __device__ __forceinline__ unsigned pack2bf(float a, float b) {
    return (unsigned)f2bf(a) | ((unsigned)f2bf(b) << 16);
}
static __device__ __forceinline__ float ldf(const void* p, int i, bool isf32) {
    return isf32 ? ((const float*)p)[i] : bf2f(((const unsigned short*)p)[i]);
}
// zero a gathered row-quarter when the edge slot is past the end (masked ILP)
static __device__ __forceinline__ uint4 zsel(uint4 u, int v) {
    return v ? u : make_uint4(0u, 0u, 0u, 0u);
}
// unpack 8 bf16 (4 dwords) and accumulate into 8 floats
static __device__ __forceinline__ void acc8(float a[8], uint4 u) {
    unsigned w[4] = {u.x, u.y, u.z, u.w};
#pragma unroll
    for (int p = 0; p < 4; ++p) {
        a[2 * p]     += __uint_as_float(w[p] << 16);
        a[2 * p + 1] += __uint_as_float(w[p] & 0xffff0000u);
    }
}

// ---- dtype sniffer ----
__global__ __launch_bounds__(64) void k_sniff(const unsigned int* __restrict__ x,
                                              int* __restrict__ flag) {
    int bad = 0;
    for (int i = threadIdx.x; i < 1024; i += 64) {
        float v = __uint_as_float((x[i] & 0xffffu) << 16);
        if (!(fabsf(v) < 1e6f)) bad = 1;
    }
    unsigned long long m = __ballot(bad);
    if (threadIdx.x == 0) *flag = (m != 0ull) ? 1 : 0;
}

// ---- fine-bucket histogram via LDS ----
__global__ __launch_bounds__(256) void k_bhist(const int* __restrict__ dst,
                                               int* __restrict__ fhist) {
    __shared__ int h[2048];
    int tid = threadIdx.x;
    for (int i = tid; i < 2048; i += 256) h[i] = 0;
    __syncthreads();
    int i = blockIdx.x * 256 + tid;
    int stride = gridDim.x * 256;
    for (int e = i; e < N_EDGES; e += stride) {
        unsigned d = (unsigned)dst[e];
        if (d < N_NODES) atomicAdd(&h[d >> 8], 1);
    }
    __syncthreads();
    for (int i2 = tid; i2 < 2048; i2 += 256)
        if (h[i2]) atomicAdd(&fhist[i2], h[i2]);
}

// ---- single-block exclusive scan over fine buckets; emits cursors ----
__global__ __launch_bounds__(256) void k_scanf(const int* __restrict__ fhist,
                                               int* __restrict__ fbase,
                                               int* __restrict__ bcur,
                                               int* __restrict__ acur) {
    __shared__ int tmp[256];
    __shared__ int s_run;
    int tid = threadIdx.x;
    if (tid == 0) s_run = 0;
    __syncthreads();
    for (int base = 0; base < 2048; base += 256) {
        int i = base + tid;
        int v = (i < NFINE) ? fhist[i] : 0;
        int val = v;
        tmp[tid] = val;
        __syncthreads();
        for (int o = 1; o < 256; o <<= 1) {
            int t = (tid >= o) ? tmp[tid - o] : 0;
            __syncthreads();
            val += t;
            tmp[tid] = val;
            __syncthreads();
        }
        int run = s_run;
        if (i < NFINE) {
            int ex = run + val - v;
            fbase[i] = ex;
            bcur[i] = ex;
            if ((i & 31) == 0) acur[i >> 5] = ex;
        }
        __syncthreads();
        if (tid == 255) s_run = run + val;
        __syncthreads();
    }
    if (tid == 0) fbase[NFINE] = s_run;
}

// ---- multisplit level A: raw edges -> 62 coarse buckets ----
__global__ __launch_bounds__(256) void k_scatA(const int* __restrict__ src,
                                               const int* __restrict__ dst,
                                               int* __restrict__ acur,
                                               unsigned* __restrict__ ebufA) {
    __shared__ unsigned stage[NCOARSE * CAPA];
    __shared__ int lcnt[NCOARSE], nn[NCOARSE], soff[NCOARSE], sbase[NCOARSE];
    __shared__ int stot;
    int tid = threadIdx.x;
    int cb = blockIdx.x * 8192;
    if (tid < NCOARSE) lcnt[tid] = 0;
    __syncthreads();
    for (int i = 0; i < 32; ++i) {
        int e = cb + (i << 8) + tid;
        if (e < N_EDGES) {
            unsigned d = (unsigned)dst[e], s = (unsigned)src[e];
            if (d < N_NODES) {
                unsigned b = d >> 13;
                unsigned p = ((d & 8191u) << 19) | s;
                int pos = atomicAdd(&lcnt[b], 1);
                if (pos < CAPA) stage[b * CAPA + pos] = p;
                else { int slot = atomicAdd(&acur[b], 1); ebufA[slot] = p; }
            }
        }
    }
    __syncthreads();
    if (tid < NCOARSE) nn[tid] = min(lcnt[tid], CAPA);
    __syncthreads();
    if (tid == 0) {
        int r = 0;
        for (int b = 0; b < NCOARSE; ++b) { soff[b] = r; r += nn[b]; }
        stot = r;
    }
    __syncthreads();
    if (tid < NCOARSE && nn[tid] > 0) sbase[tid] = atomicAdd(&acur[tid], nn[tid]);
    __syncthreads();
    for (int i = tid; i < stot; i += 256) {
        int lo = 0, hi = NCOARSE - 1;
        while (lo < hi) { int mid = (lo + hi + 1) >> 1; if (soff[mid] <= i) lo = mid; else hi = mid - 1; }
        int r = i - soff[lo];
        ebufA[sbase[lo] + r] = stage[lo * CAPA + r];
    }
}

// ---- multisplit level B: coarse -> 32 fine buckets ----
__global__ __launch_bounds__(256) void k_scatB(const unsigned* __restrict__ ebufA,
                                               const int* __restrict__ fbase,
                                               int* __restrict__ bcur,
                                               unsigned* __restrict__ ebufB) {
    __shared__ unsigned stage[32 * CAPB];
    __shared__ int lcnt[32], nn[32], soff[32], sbase[32];
    __shared__ int stot;
    int tid = threadIdx.x;
    int a = blockIdx.x >> 3, sub = blockIdx.x & 7;
    int f0 = a * 32;
    int lb = min(32, NFINE - f0);
    int abase = fbase[f0];
    int aend = fbase[min(f0 + 32, NFINE)];
    for (int cb = abase + sub * 8192; cb < aend; cb += 8 * 8192) {
        if (tid < 32) lcnt[tid] = 0;
        __syncthreads();
        for (int i = 0; i < 32; ++i) {
            int e = cb + (i << 8) + tid;
            if (e < aend) {
                unsigned p = ebufA[e];
                unsigned dl13 = p >> 19;
                unsigned s = p & 0x7FFFFu;
                unsigned j = dl13 >> 8;
                unsigned q = ((dl13 & 255u) << 19) | s;
                int pos = atomicAdd(&lcnt[j], 1);
                if (pos < CAPB) stage[j * CAPB + pos] = q;
                else { int slot = atomicAdd(&bcur[f0 + j], 1); ebufB[slot] = q; }
            }
        }
        __syncthreads();
        if (tid < 32) nn[tid] = (tid < lb) ? min(lcnt[tid], CAPB) : 0;
        __syncthreads();
        if (tid == 0) {
            int r = 0;
            for (int b = 0; b < 32; ++b) { soff[b] = r; r += nn[b]; }
            stot = r;
        }
        __syncthreads();
        if (tid < 32 && nn[tid] > 0) sbase[tid] = atomicAdd(&bcur[f0 + tid], nn[tid]);
        __syncthreads();
        for (int i = tid; i < stot; i += 256) {
            int lo = 0, hi = 31;
            while (lo < hi) { int mid = (lo + hi + 1) >> 1; if (soff[mid] <= i) lo = mid; else hi = mid - 1; }
            int r = i - soff[lo];
            ebufB[sbase[lo] + r] = stage[lo * CAPB + r];
        }
        __syncthreads();
    }
}

// ---- CSR build per fine bucket ----
__global__ __launch_bounds__(256) void k_csr(const unsigned* __restrict__ ebufB,
                                             const int* __restrict__ fbase,
                                             int* __restrict__ csr,
                                             int* __restrict__ off,
                                             float* __restrict__ dinv) {
    __shared__ int cnt[256], ctmp[256], ccur[256];
    int tid = threadIdx.x;
    int b = blockIdx.x;
    int base = fbase[b];
    int n = fbase[b + 1] - base;
    cnt[tid] = 0;
    __syncthreads();
    for (int i = tid; i < n; i += 256) {
        unsigned dl = ebufB[base + i] >> 19;
        atomicAdd(&cnt[dl], 1);
    }
    __syncthreads();
    int v = cnt[tid];
    int val = v;
    ctmp[tid] = val;
    __syncthreads();
    for (int o = 1; o < 256; o <<= 1) {
        int t = (tid >= o) ? ctmp[tid - o] : 0;
        __syncthreads();
        val += t;
        ctmp[tid] = val;
        __syncthreads();
    }
    int excl = val - v;
    off[b * 256 + tid] = base + excl;
    ccur[tid] = excl;
    dinv[b * 256 + tid] = rsqrtf((float)v + 1.0f);
    __syncthreads();
    for (int i = tid; i < n; i += 256) {
        unsigned p = ebufB[base + i];
        unsigned dl = p >> 19;
        int slot = atomicAdd(&ccur[dl], 1);
        csr[base + slot] = (int)(p & 0x7FFFFu);
    }
}

// ---- y1 = (x @ W1) * dinv  -> bf16 rows (32 x bf16 = 64B) ----
// Re-blocked: 4 nodes x 8 cols per thread. Per k-element each thread reads
// only its 8-col W slice (2 b128) amortized over 4 nodes -> 4x fewer uniform
// LDS reads per FMA, 4-node ILP on the x-row load stream. Lanes sharing a
// node-quad issue identical x addresses (HW broadcast, no extra traffic).
__global__ __launch_bounds__(256) void k_gemm1(const void* __restrict__ x,
                                               const void* __restrict__ w1,
                                               const float* __restrict__ dinv,
                                               unsigned* __restrict__ y1b,
                                               const int* __restrict__ flag) {
    __shared__ float wlds[IN_DIM * H1];
    const bool isf32 = (*flag != 0);
    for (int i = threadIdx.x; i < IN_DIM * H1; i += 256) wlds[i] = ldf(w1, i, isf32);
    __syncthreads();
    const int tid = threadIdx.x;
    const int c = tid & 3;                 // col group: cols 8c..8c+7
    const int q = tid >> 2;                // node quad within block
    const int n0 = blockIdx.x * 256 + q * 4;

    int nn[4];
#pragma unroll
    for (int i = 0; i < 4; ++i) nn[i] = min(n0 + i, N_NODES - 1);

    float acc[4][8];
#pragma unroll
    for (int i = 0; i < 4; ++i)
#pragma unroll
        for (int j = 0; j < 8; ++j) acc[i][j] = 0.f;

    if (isf32) {
        const float4* xp0 = reinterpret_cast<const float4*>((const float*)x + (size_t)nn[0] * IN_DIM);
        const float4* xp1 = reinterpret_cast<const float4*>((const float*)x + (size_t)nn[1] * IN_DIM);
        const float4* xp2 = reinterpret_cast<const float4*>((const float*)x + (size_t)nn[2] * IN_DIM);
        const float4* xp3 = reinterpret_cast<const float4*>((const float*)x + (size_t)nn[3] * IN_DIM);
#pragma unroll 4
        for (int kk = 0; kk < IN_DIM / 4; ++kk) {
            float4 v0 = xp0[kk], v1 = xp1[kk], v2 = xp2[kk], v3 = xp3[kk];
            float xa[4][4] = {{v0.x, v0.y, v0.z, v0.w},
                              {v1.x, v1.y, v1.z, v1.w},
                              {v2.x, v2.y, v2.z, v2.w},
                              {v3.x, v3.y, v3.z, v3.w}};
            const float* wr = &wlds[(kk * 4) * H1 + 8 * c];
#pragma unroll
            for (int p = 0; p < 4; ++p) {
                float w8[8];
#pragma unroll
                for (int j = 0; j < 8; ++j) w8[j] = wr[p * H1 + j];
#pragma unroll
                for (int i = 0; i < 4; ++i)
#pragma unroll
                    for (int j = 0; j < 8; ++j) acc[i][j] += xa[i][p] * w8[j];
            }
        }
    } else {
        const uint4* xp0 = reinterpret_cast<const uint4*>((const unsigned short*)x + (size_t)nn[0] * IN_DIM);
        const uint4* xp1 = reinterpret_cast<const uint4*>((const unsigned short*)x + (size_t)nn[1] * IN_DIM);
        const uint4* xp2 = reinterpret_cast<const uint4*>((const unsigned short*)x + (size_t)nn[2] * IN_DIM);
        const uint4* xp3 = reinterpret_cast<const uint4*>((const unsigned short*)x + (size_t)nn[3] * IN_DIM);
#pragma unroll 2
        for (int kk = 0; kk < IN_DIM / 8; ++kk) {
            uint4 b0 = xp0[kk], b1 = xp1[kk], b2 = xp2[kk], b3 = xp3[kk];
            unsigned ua[4][4] = {{b0.x, b0.y, b0.z, b0.w},
                                 {b1.x, b1.y, b1.z, b1.w},
                                 {b2.x, b2.y, b2.z, b2.w},
                                 {b3.x, b3.y, b3.z, b3.w}};
            const float* wr = &wlds[(kk * 8) * H1 + 8 * c];
#pragma unroll
            for (int p = 0; p < 4; ++p) {
                float wlo[8], whi[8];
#pragma unroll
                for (int j = 0; j < 8; ++j) wlo[j] = wr[(2 * p) * H1 + j];
#pragma unroll
                for (int j = 0; j < 8; ++j) whi[j] = wr[(2 * p + 1) * H1 + j];
#pragma unroll
                for (int i = 0; i < 4; ++i) {
                    float xlo = __uint_as_float(ua[i][p] << 16);
                    float xhi = __uint_as_float(ua[i][p] & 0xffff0000u);
#pragma unroll
                    for (int j = 0; j < 8; ++j) acc[i][j] += xlo * wlo[j];
#pragma unroll
                    for (int j = 0; j < 8; ++j) acc[i][j] += xhi * whi[j];
                }
            }
        }
    }
#pragma unroll
    for (int i = 0; i < 4; ++i) {
        int node = n0 + i;
        if (node >= N_NODES) break;
        float s = dinv[node];
        uint4 o;
        o.x = pack2bf(acc[i][0] * s, acc[i][1] * s);
        o.y = pack2bf(acc[i][2] * s, acc[i][3] * s);
        o.z = pack2bf(acc[i][4] * s, acc[i][5] * s);
        o.w = pack2bf(acc[i][6] * s, acc[i][7] * s);
        *reinterpret_cast<uint4*>(y1b + (size_t)node * 16 + 4 * c) = o;
    }
}

// ---- pull layer 1: 4 lanes/node, uint4 (16B) row-quarter gathers ----
__global__ __launch_bounds__(256) void k_pull1(const int* __restrict__ off,
                                               const int* __restrict__ csr,
                                               const unsigned* __restrict__ y1b,
                                               const float* __restrict__ dinv,
                                               const void* __restrict__ b1,
                                               const void* __restrict__ w2,
                                               unsigned* __restrict__ y2b,
                                               const int* __restrict__ flag) {
    __shared__ float w2l[H1 * H2];
    __shared__ float b1l[H1];
    __shared__ float hbuf[64 * 33];      // stride 33: conflict-free at 16 grp/wave
    const bool isf32 = (*flag != 0);
    int tid = threadIdx.x;
    for (int i = tid; i < H1 * H2; i += 256) w2l[i] = ldf(w2, i, isf32);
    if (tid < H1) b1l[tid] = ldf(b1, tid, isf32);
    __syncthreads();

    const int r = tid & 3;               // lane within node: dims [8r, 8r+8)
    const int g = tid >> 2;              // node slot in block (0..63)
    const int node = blockIdx.x * 64 + g;
    if (node >= N_NODES) return;

    float a[8];
#pragma unroll
    for (int p = 0; p < 8; ++p) a[p] = 0.f;

    const int beg = off[node], end = off[node + 1];
    const unsigned* yb = y1b + 4 * r;
    for (int j = beg; j < end; j += 4) {
        const int e1 = end - 1;
        int i1 = min(j + 1, e1), i2 = min(j + 2, e1), i3 = min(j + 3, e1);
        int s0 = csr[j], s1 = csr[i1], s2 = csr[i2], s3 = csr[i3];
        uint4 u0 = *reinterpret_cast<const uint4*>(yb + (size_t)s0 * 16);
        uint4 u1 = *reinterpret_cast<const uint4*>(yb + (size_t)s1 * 16);
        uint4 u2 = *reinterpret_cast<const uint4*>(yb + (size_t)s2 * 16);
        uint4 u3 = *reinterpret_cast<const uint4*>(yb + (size_t)s3 * 16);
        u1 = zsel(u1, j + 1 < end);
        u2 = zsel(u2, j + 2 < end);
        u3 = zsel(u3, j + 3 < end);
        acc8(a, u0); acc8(a, u1); acc8(a, u2); acc8(a, u3);
    }
    // self term (pre-scaled by dinv in gemm1)
    uint4 su = *reinterpret_cast<const uint4*>(yb + (size_t)node * 16);
    acc8(a, su);

    const float sc = dinv[node];
    float* hb = &hbuf[g * 33];
#pragma unroll
    for (int p = 0; p < 8; ++p) {
        float h = sc * a[p] + b1l[8 * r + p];
        hb[8 * r + p] = h > 0.f ? h : 0.f;   // same-wave readers only
    }
    float z[4];
#pragma unroll
    for (int c = 0; c < 4; ++c) z[c] = 0.f;
#pragma unroll
    for (int k = 0; k < H1; ++k) {
        float hv = hb[k];
#pragma unroll
        for (int c = 0; c < 4; ++c) z[c] += hv * w2l[k * H2 + 4 * r + c];
    }
    uint2 o;
    o.x = pack2bf(sc * z[0], sc * z[1]);
    o.y = pack2bf(sc * z[2], sc * z[3]);
    *reinterpret_cast<uint2*>(y2b + (size_t)node * 8 + 2 * r) = o;
}

// ---- pull layer 2: 2 lanes/node, uint4 (16B) half-row gathers ----
__global__ __launch_bounds__(256) void k_pull2(const int* __restrict__ off,
                                               const int* __restrict__ csr,
                                               const unsigned* __restrict__ y2b,
                                               const float* __restrict__ dinv,
                                               const void* __restrict__ b2,
                                               const void* __restrict__ wfc,
                                               const void* __restrict__ bfc,
                                               void* __restrict__ out,
                                               const int* __restrict__ flag) {
    __shared__ float wl[H2 * 2];
    __shared__ float b2l[H2];
    __shared__ float bfl[2];
    const bool isf32 = (*flag != 0);
    int tid = threadIdx.x;
    if (tid < H2 * 2) wl[tid] = ldf(wfc, tid, isf32);
    if (tid < H2) b2l[tid] = ldf(b2, tid, isf32);
    if (tid < 2) bfl[tid] = ldf(bfc, tid, isf32);
    __syncthreads();

    const int r = tid & 1;               // lane within node: dims [8r, 8r+8)
    const int node = blockIdx.x * 128 + (tid >> 1);
    if (node >= N_NODES) return;

    float a[8];
#pragma unroll
    for (int p = 0; p < 8; ++p) a[p] = 0.f;

    const int beg = off[node], end = off[node + 1];
    const unsigned* yb = y2b + 4 * r;
    for (int j = beg; j < end; j += 4) {
        const int e1 = end - 1;
        int i1 = min(j + 1, e1), i2 = min(j + 2, e1), i3 = min(j + 3, e1);
        int s0 = csr[j], s1 = csr[i1], s2 = csr[i2], s3 = csr[i3];
        uint4 u0 = *reinterpret_cast<const uint4*>(yb + (size_t)s0 * 8);
        uint4 u1 = *reinterpret_cast<const uint4*>(yb + (size_t)s1 * 8);
        uint4 u2 = *reinterpret_cast<const uint4*>(yb + (size_t)s2 * 8);
        uint4 u3 = *reinterpret_cast<const uint4*>(yb + (size_t)s3 * 8);
        u1 = zsel(u1, j + 1 < end);
        u2 = zsel(u2, j + 2 < end);
        u3 = zsel(u3, j + 3 < end);
        acc8(a, u0); acc8(a, u1); acc8(a, u2); acc8(a, u3);
    }
    // self term (pre-scaled)
    uint4 su = *reinterpret_cast<const uint4*>(yb + (size_t)node * 8);
    acc8(a, su);

    const float sc = dinv[node];
    float l0 = 0.f, l1 = 0.f;
#pragma unroll
    for (int p = 0; p < 8; ++p) {
        float h = sc * a[p] + b2l[8 * r + p];
        h = h > 0.f ? h : 0.f;
        l0 += h * wl[(8 * r + p) * 2];
        l1 += h * wl[(8 * r + p) * 2 + 1];
    }
    l0 += __shfl_xor(l0, 1, 64);         // combine lane pair (same node)
    l1 += __shfl_xor(l1, 1, 64);
    if (r == 0) {
        l0 += bfl[0];
        l1 += bfl[1];
        float mx = fmaxf(l0, l1);
        float lse = mx + logf(__expf(l0 - mx) + __expf(l1 - mx));
        if (isf32) {
            reinterpret_cast<float2*>(out)[node] = make_float2(l0 - lse, l1 - lse);
        } else {
            reinterpret_cast<unsigned*>(out)[node] =
                (unsigned)f2bf(l0 - lse) | ((unsigned)f2bf(l1 - lse) << 16);
        }
    }
}

extern "C" void kernel_launch(void* const* d_in, const int* in_sizes, int n_in,
                              void* d_out, int out_size, void* d_ws, size_t ws_size,
                              hipStream_t stream) {
    const void* x   = d_in[0];
    const int*  ei  = (const int*)d_in[1];
    const void* w1  = d_in[2];
    const void* b1  = d_in[3];
    const void* w2  = d_in[4];
    const void* b2  = d_in[5];
    const void* wfc = d_in[6];
    const void* bfc = d_in[7];
    const int* src = ei;
    const int* dst = ei + N_EDGES;

    // workspace (4B units), ~116 MB. csr overlays ebufA (dead after k_scatB).
    float*    ws    = (float*)d_ws;
    int*      flag  = (int*)ws;
    float*    dinv  = ws + 64;
    int*      fhist = (int*)(ws + 500288);
    int*      fbase = (int*)(ws + 502336);
    int*      acur  = (int*)(ws + 504384);
    int*      bcur  = (int*)(ws + 504448);
    int*      off   = (int*)(ws + 506496);
    unsigned* ebufA = (unsigned*)(ws + 1006784);
    int*      csr   = (int*)(ws + 1006784);     // reuses ebufA
    unsigned* ebufB = (unsigned*)(ws + 9006784);
    unsigned* y1b   = (unsigned*)(ws + 17006784);
    unsigned* y2b   = (unsigned*)(ws + 25010368);

    k_sniff<<<1, 64, 0, stream>>>((const unsigned int*)x, flag);
    hipMemsetAsync(fhist, 0, 2048 * sizeof(int), stream);
    k_bhist<<<256, 256, 0, stream>>>(dst, fhist);
    k_scanf<<<1, 256, 0, stream>>>(fhist, fbase, bcur, acur);
    k_scatA<<<977, 256, 0, stream>>>(src, dst, acur, ebufA);
    k_scatB<<<NCOARSE * 8, 256, 0, stream>>>(ebufA, fbase, bcur, ebufB);
    k_csr<<<NFINE, 256, 0, stream>>>(ebufB, fbase, csr, off, dinv);
    k_gemm1<<<NFINE, 256, 0, stream>>>(x, w1, dinv, y1b, flag);
    k_pull1<<<(N_NODES + 63) / 64, 256, 0, stream>>>(off, csr, y1b, dinv, b1, w2, y2b, flag);
    k_pull2<<<(N_NODES + 127) / 128, 256, 0, stream>>>(off, csr, y2b, dinv, b2, wfc, bfc, d_out, flag);
}